// Round 6
// baseline (266.273 us; speedup 1.0000x reference)
//
#include <hip/hip_runtime.h>

// dims: B=16 W=32 M=512 NH=64 HALF=32 K=8 H=8 LK=16 LOUT=2 NSP=10 GCIN=24
// rows = B*M = 8192. Reference dtypes fp32; bf16 internally for MFMA.
// 4 dispatches: fused1(rnn+e+conv+rg | wbt | zero), amx,
// gemm_adjmix_h1 (merged K3+K4), ospout(+final proj).
// R6: gemm_adjmix_h1 reworked -- 16-row panels (grid 512 = 2 blocks/CU) +
// register prefetch depth 2 (loads issued 2 iters ahead; unroll-2 keeps
// buffer index static). R5's depth-1 @ 1 block/CU exposed ~500cy of L3
// latency per k-iteration (44us, Occ 9.4%, all pipes <22%).

typedef __attribute__((ext_vector_type(8))) short bf16x8;
typedef __attribute__((ext_vector_type(4))) float f32x4;
#define MFMA16 __builtin_amdgcn_mfma_f32_16x16x32_bf16

__device__ __forceinline__ unsigned short f2bf(float f) {
    unsigned u = __float_as_uint(f);
    u += 0x7fff + ((u >> 16) & 1);          // RNE
    return (unsigned short)(u >> 16);
}
__device__ __forceinline__ float bf2f(unsigned short h) {
    return __uint_as_float(((unsigned)h) << 16);
}
__device__ __forceinline__ float fast_tanh(float x) {
    float e = __expf(2.f * x);
    return 1.f - 2.f / (e + 1.f);
}

// ---------------- K1: fused1 ----------------------------------------------
__global__ __launch_bounds__(256) void fused1_kernel(
    const float* __restrict__ x, const float* __restrict__ Wih,
    const float* __restrict__ Whh, const float* __restrict__ bih,
    const float* __restrict__ bhh, const float* __restrict__ W1,
    const float* __restrict__ W2, float* __restrict__ lh,
    float* __restrict__ e1, float* __restrict__ e2,
    const float* __restrict__ conv_w, const float* __restrict__ conv_b,
    const float* __restrict__ convl_w, const float* __restrict__ convl_b,
    const float* __restrict__ gc1_w, unsigned short* __restrict__ rgT,
    const float* __restrict__ Wb, unsigned short* __restrict__ WbT,
    float* __restrict__ nrmss)
{
    __shared__ __align__(16) char smem[12160];
    int blk = blockIdx.x, t = threadIdx.x;

    if (blk < 256) {
        int wid = t >> 6, lane = t & 63;
        int rowblk = blk * 32;
        int b = rowblk >> 9, mb = rowblk & 511;
        float* xs = (float*)smem;                               // [32][32]
        unsigned short* hs = (unsigned short*)(smem + 4096);    // [2][16][72]
        float* rrs = (float*)(smem + 8704);                     // [32][25]

        for (int u = t; u < 1024; u += 256) {
            int tt = u >> 5, c = u & 31;
            xs[tt * 32 + c] = x[(b * 32 + tt) * 512 + mb + c];
        }
        for (int u = t; u < 2304; u += 256) hs[u] = 0;
        __syncthreads();

        if (wid < 2) {
            // RNN (waves 0,1; 16 series each)
            int l15 = lane & 15, quad = lane >> 4;
            int row0 = rowblk + wid * 16;
            unsigned short* hw0 = hs + wid * 1152;

            bf16x8 afr[4][2];
#pragma unroll
            for (int mt = 0; mt < 4; ++mt)
#pragma unroll
                for (int hf = 0; hf < 2; ++hf) {
                    const float* src = Whh + (16 * mt + l15) * 64 + 32 * hf + quad * 8;
                    union { bf16x8 v; unsigned short u[8]; } tmp;
#pragma unroll
                    for (int j = 0; j < 8; ++j) tmp.u[j] = f2bf(src[j]);
                    afr[mt][hf] = tmp.v;
                }
            bf16x8 wfr[2][2][2];
#pragma unroll
            for (int e = 0; e < 2; ++e)
#pragma unroll
                for (int nt = 0; nt < 2; ++nt)
#pragma unroll
                    for (int kf = 0; kf < 2; ++kf) {
                        const float* Wsrc = (e ? W2 : W1);
                        const float* src = Wsrc + (16 * nt + l15) * 64 + 32 * kf + quad * 8;
                        union { bf16x8 v; unsigned short u[8]; } tmp;
#pragma unroll
                        for (int j = 0; j < 8; ++j) tmp.u[j] = f2bf(src[j]);
                        wfr[e][nt][kf] = tmp.v;
                    }
            float wihv[4][4], bsv[4][4];
#pragma unroll
            for (int mt = 0; mt < 4; ++mt)
#pragma unroll
                for (int r = 0; r < 4; ++r) {
                    int n = 16 * mt + quad * 4 + r;
                    wihv[mt][r] = Wih[n];
                    bsv[mt][r]  = bih[n] + bhh[n];
                }

            float th[4][4];
            for (int tstep = 0; tstep < 32; ++tstep) {
                bf16x8 b0 = *(bf16x8*)(hw0 + l15 * 72 + quad * 8);
                bf16x8 b1 = *(bf16x8*)(hw0 + l15 * 72 + 32 + quad * 8);
                float xt = xs[tstep * 32 + wid * 16 + l15];
                f32x4 acc[4];
#pragma unroll
                for (int mt = 0; mt < 4; ++mt) {
                    f32x4 z = {0.f, 0.f, 0.f, 0.f};
                    acc[mt] = MFMA16(afr[mt][0], b0, z, 0, 0, 0);
                    acc[mt] = MFMA16(afr[mt][1], b1, acc[mt], 0, 0, 0);
                }
#pragma unroll
                for (int mt = 0; mt < 4; ++mt) {
                    ushort4 hwv;
#pragma unroll
                    for (int r = 0; r < 4; ++r)
                        th[mt][r] = fast_tanh(acc[mt][r] + xt * wihv[mt][r] + bsv[mt][r]);
                    hwv.x = f2bf(th[mt][0]); hwv.y = f2bf(th[mt][1]);
                    hwv.z = f2bf(th[mt][2]); hwv.w = f2bf(th[mt][3]);
                    *(ushort4*)(hw0 + l15 * 72 + 16 * mt + quad * 4) = hwv;
                }
            }
#pragma unroll
            for (int mt = 0; mt < 4; ++mt)
                *(float4*)(lh + (row0 + l15) * 64 + 16 * mt + quad * 4) =
                    make_float4(th[mt][0], th[mt][1], th[mt][2], th[mt][3]);

            bf16x8 a0 = *(bf16x8*)(hw0 + l15 * 72 + quad * 8);
            bf16x8 a1 = *(bf16x8*)(hw0 + l15 * 72 + 32 + quad * 8);
#pragma unroll
            for (int e = 0; e < 2; ++e) {
                float* dst = e ? e2 : e1;
#pragma unroll
                for (int nt = 0; nt < 2; ++nt) {
                    f32x4 z = {0.f, 0.f, 0.f, 0.f};
                    f32x4 ee = MFMA16(a0, wfr[e][nt][0], z, 0, 0, 0);
                    ee = MFMA16(a1, wfr[e][nt][1], ee, 0, 0, 0);
#pragma unroll
                    for (int r = 0; r < 4; ++r)
                        dst[(row0 + quad * 4 + r) * 32 + 16 * nt + l15] = ee[r];
                }
            }
        } else {
            // conv + rg (waves 2,3; 16 rows each)
            int wid2 = wid - 2;
#pragma unroll
            for (int rep = 0; rep < 2; ++rep) {
                int task = rep * 64 + lane;            // 128 tasks = 16 rows x 8 k
                int rl = wid2 * 16 + (task >> 3);
                int k  = task & 7;
                float s = conv_b[k];
                for (int w = 0; w < 32; ++w) s += xs[w * 32 + rl] * conv_w[k * 32 + w];
                float l0 = convl_b[k], l1 = l0;
                for (int tt = 0; tt < 16; ++tt) {
                    float wv = convl_w[k * 16 + tt];
                    l0 += xs[(2 * tt) * 32 + rl] * wv;
                    l1 += xs[(2 * tt + 1) * 32 + rl] * wv;
                }
                rrs[rl * 25 + k * 3 + 0] = fmaxf(s, 0.f);
                rrs[rl * 25 + k * 3 + 1] = fmaxf(l0, 0.f);
                rrs[rl * 25 + k * 3 + 2] = fmaxf(l1, 0.f);
            }
            // intra-wave LDS RAW: in-order DS per wave; no cross-wave dep
            __builtin_amdgcn_wave_barrier();
            int rl = wid2 * 16 + (lane & 15);
            int nb = lane >> 4;
#pragma unroll
            for (int q = 0; q < 16; ++q) {
                int n = nb * 16 + q;
                float acc = 0.f;
#pragma unroll
                for (int c = 0; c < 24; ++c) acc += rrs[rl * 25 + c] * gc1_w[c * 64 + n];
                rgT[b * 32768 + n * 512 + mb + rl] = f2bf(acc);
            }
        }
    } else if (blk < 512) {
        // ---------------- Wb transpose ----------------
        int bid = blk - 256;
        int nb = (bid & 15) * 32, kb = (bid >> 4) * 32;
        float* tile = (float*)smem;             // [32][33]
        for (int u = t; u < 1024; u += 256) {
            int r = u >> 5, c = u & 31;
            tile[r * 33 + c] = Wb[(kb + r) * 512 + nb + c];
        }
        __syncthreads();
        for (int u = t; u < 1024; u += 256) {
            int r = u >> 5, c = u & 31;
            WbT[(nb + r) * 512 + kb + c] = f2bf(tile[c * 33 + r]);
        }
    } else {
        nrmss[(blk - 512) * 256 + t] = 0.f;
    }
}

// ---------------- K2: a_mx 4x4/thread, factorized exp, fused sumsq --------
__global__ __launch_bounds__(256) void amx_kernel(
    const float* __restrict__ e1, const float* __restrict__ e2,
    const float* __restrict__ b1p, const float* __restrict__ Vp,
    const float* __restrict__ bvp, unsigned short* __restrict__ amxb,
    float* __restrict__ nrmss)
{
    int bb = blockIdx.z;
    int i0 = blockIdx.y * 64, j0 = blockIdx.x * 64;
    __shared__ float e2s[64][33], e1s[64][33];
    __shared__ float Vs[32];
    __shared__ float red[16][68];
    int t = threadIdx.x;
    for (int u = t; u < 2048; u += 256) {
        int r = u >> 5, c = u & 31;
        e2s[r][c] = e2[(bb * 512 + i0 + r) * 32 + c];
        e1s[r][c] = e1[(bb * 512 + j0 + r) * 32 + c] + b1p[c];
    }
    if (t < 32) Vs[t] = Vp[t];
    __syncthreads();
    int ti = (t >> 4) * 4, tj = (t & 15) * 4;
    float acc[4][4] = {};
#pragma unroll
    for (int h = 0; h < 32; ++h) {
        float vv = Vs[h];
        float xi[4], yj[4], Exi[4], Eyj[4];
#pragma unroll
        for (int p = 0; p < 4; ++p) { xi[p] = e2s[ti + p][h]; Exi[p] = __expf(xi[p]); }
#pragma unroll
        for (int q = 0; q < 4; ++q) { yj[q] = e1s[tj + q][h]; Eyj[q] = __expf(yj[q]); }
#pragma unroll
        for (int p = 0; p < 4; ++p)
#pragma unroll
            for (int q = 0; q < 4; ++q) {
                float v = xi[p] + yj[q];
                float prod = Exi[p] * Eyj[q];
                float el = v > 0.f ? v : prod - 1.f;  // exp(xi+yj)=Exi*Eyj
                acc[p][q] += vv * el;
            }
    }
    float bv = bvp[0];
    float ss[4] = {0.f, 0.f, 0.f, 0.f};
#pragma unroll
    for (int p = 0; p < 4; ++p) {
        float v0 = acc[p][0] + bv, v1 = acc[p][1] + bv;
        float v2 = acc[p][2] + bv, v3 = acc[p][3] + bv;
        ushort4 o;
        o.x = f2bf(v0); o.y = f2bf(v1); o.z = f2bf(v2); o.w = f2bf(v3);
        *(ushort4*)(amxb + (bb * 512 + i0 + ti + p) * 512 + j0 + tj) = o;
        ss[0] += v0 * v0; ss[1] += v1 * v1; ss[2] += v2 * v2; ss[3] += v3 * v3;
    }
#pragma unroll
    for (int q = 0; q < 4; ++q) red[t >> 4][tj + q] = ss[q];
    __syncthreads();
    if (t < 64) {
        float s = 0.f;
#pragma unroll
        for (int g = 0; g < 16; ++g) s += red[g][t];
        atomicAdd(&nrmss[bb * 512 + j0 + t], s);
    }
}

// ---------------- K3: gemm_adjmix + gemm_h1 merged, 16-row panels ---------
// Grid dim3(32,16): block owns rows (bb, i0:i0+16). Part A: 8 j-tiles x 8
// k-tiles, wrap-ordered (last k-tile == j-tile -> As reuse in epilogue),
// register prefetch DEPTH 2 (unroll-2 keeps buffer index static). Part B:
// h1 from own just-written adjmix rows (same-CU L2-hot).
__global__ __launch_bounds__(256) void gemm_adjmix_h1(
    const unsigned short* __restrict__ amxb, const unsigned short* __restrict__ WbT,
    const float* __restrict__ wbp, const float* __restrict__ adj,
    const float* __restrict__ nrmss, unsigned short* __restrict__ adjmixb,
    const unsigned short* __restrict__ rgT, const float* __restrict__ gc1_b,
    const float* __restrict__ gc2_w, float* __restrict__ h1g)
{
    const int bb = blockIdx.y;
    const int i0 = blockIdx.x * 16;
    __shared__ __align__(16) char smem[16128];
    short* As = (short*)smem;                           // [16][72] = 2304
    short* Bs = (short*)(smem + 2304);                  // [64][72] = 9216 -> 11520
    float* rn = (float*)(smem + 11520);                 // [512] (dead in part B)
    float (*h1s)[72] = (float (*)[72])(smem + 11520);   // [16][72] overlay

    const int t = threadIdx.x, w = t >> 6, lane = t & 63;
    const int l15 = lane & 15, quad = lane >> 4;
    const int siA = t >> 3, soA = t & 7;    // t<128: A stage (16 rows x 8 chunks)
    const int iB = t >> 3, oB = t & 7;      // B stage rows iB and iB+32

    for (int u = t; u < 512; u += 256)
        rn[u] = 1.f / fmaxf(sqrtf(nrmss[bb * 512 + u]), 1e-12f);
    const unsigned short* Ag = amxb + bb * 262144;
    const float wb = wbp[0];

    // ---- Part A: adjmix rows, 64 iters, depth-2 reg prefetch -------------
    int4 pa[2], pb0[2], pb1[2];
    auto ldTile = [&](int it, int4& A, int4& B0, int4& B1) {
        const int j0 = it >> 3, kk = it & 7;
        const int k0 = (j0 * 64 + 64 * (kk + 1)) & 511;
        if (t < 128) A = *(const int4*)(Ag + (i0 + siA) * 512 + k0 + soA * 8);
        B0 = *(const int4*)(WbT + (j0 * 64 + iB) * 512 + k0 + oB * 8);
        B1 = *(const int4*)(WbT + (j0 * 64 + 32 + iB) * 512 + k0 + oB * 8);
    };
    ldTile(0, pa[0], pb0[0], pb1[0]);
    ldTile(1, pa[1], pb0[1], pb1[1]);
    f32x4 acc;
    const f32x4 zz = {0.f, 0.f, 0.f, 0.f};
#pragma unroll 2
    for (int it = 0; it < 64; ++it) {
        const int j0 = it >> 3, kk = it & 7;
        const int k0 = (j0 * 64 + 64 * (kk + 1)) & 511;   // kk==7 -> k0==j0*64
        const int p = it & 1;
        __syncthreads();
        if (t < 128) {      // write prefetched A, scaled by rn
            union { int4 v; unsigned short us[8]; } ur; ur.v = pa[p];
            union { int4 v; unsigned short us[8]; } ow2;
#pragma unroll
            for (int c = 0; c < 8; ++c)
                ow2.us[c] = f2bf(bf2f(ur.us[c]) * rn[k0 + soA * 8 + c]);
            *(int4*)(As + siA * 72 + soA * 8) = ow2.v;
        }
        *(int4*)(Bs + iB * 72 + oB * 8) = pb0[p];
        *(int4*)(Bs + (32 + iB) * 72 + oB * 8) = pb1[p];
        if (it + 2 < 64) ldTile(it + 2, pa[p], pb0[p], pb1[p]);
        __syncthreads();
        if (kk == 0) acc = zz;
        bf16x8 a0 = *(bf16x8*)(As + l15 * 72 + quad * 8);
        bf16x8 a1 = *(bf16x8*)(As + l15 * 72 + 32 + quad * 8);
        bf16x8 b0 = *(bf16x8*)(Bs + (16 * w + l15) * 72 + quad * 8);
        bf16x8 b1 = *(bf16x8*)(Bs + (16 * w + l15) * 72 + 32 + quad * 8);
        acc = MFMA16(a0, b0, acc, 0, 0, 0);
        acc = MFMA16(a1, b1, acc, 0, 0, 0);
        if (kk == 7) {
            // As holds scaled amx(i0:+16, j0*64:+64)
#pragma unroll
            for (int r = 0; r < 4; ++r) {
                int il = quad * 4 + r;
                int jl = 16 * w + l15;
                int i = i0 + il, j = j0 * 64 + jl;
                float s  = acc[r] + wb;
                float cv = 1.f / (1.f + __expf(-s));
                float am = bf2f((unsigned short)As[il * 72 + jl]);
                float ad = adj[i * 512 + j];
                adjmixb[(bb * 512 + i) * 512 + j] = f2bf(ad * cv + am * (1.f - cv));
            }
        }
    }

    // ---- Part B: h1 from own adjmix rows + h1g ---------------------------
    const unsigned short* Ag2 = adjmixb + bb * 262144;
    const unsigned short* Bg2 = rgT + bb * 32768;
    f32x4 acc2 = zz;
    int4 qa, qb0, qb1;
    {   // prologue prefetch k0=0 (tile written at it=7, long drained)
        if (t < 128) qa = *(const int4*)(Ag2 + (i0 + siA) * 512 + soA * 8);
        qb0 = *(const int4*)(Bg2 + iB * 512 + oB * 8);
        qb1 = *(const int4*)(Bg2 + (32 + iB) * 512 + oB * 8);
    }
    for (int kt = 0; kt < 8; ++kt) {
        __syncthreads();
        if (t < 128) *(int4*)(As + siA * 72 + soA * 8) = qa;
        *(int4*)(Bs + iB * 72 + oB * 8) = qb0;
        *(int4*)(Bs + (32 + iB) * 72 + oB * 8) = qb1;
        if (kt < 7) {
            const int k0n = (kt + 1) * 64;
            if (t < 128) qa = *(const int4*)(Ag2 + (i0 + siA) * 512 + k0n + soA * 8);
            qb0 = *(const int4*)(Bg2 + iB * 512 + k0n + oB * 8);
            qb1 = *(const int4*)(Bg2 + (32 + iB) * 512 + k0n + oB * 8);
        }
        __syncthreads();
        bf16x8 a0 = *(bf16x8*)(As + l15 * 72 + quad * 8);
        bf16x8 a1 = *(bf16x8*)(As + l15 * 72 + 32 + quad * 8);
        bf16x8 b0 = *(bf16x8*)(Bs + (16 * w + l15) * 72 + quad * 8);
        bf16x8 b1 = *(bf16x8*)(Bs + (16 * w + l15) * 72 + 32 + quad * 8);
        acc2 = MFMA16(a0, b0, acc2, 0, 0, 0);
        acc2 = MFMA16(a1, b1, acc2, 0, 0, 0);
    }
#pragma unroll
    for (int r = 0; r < 4; ++r) {
        int il = quad * 4 + r;
        int j = 16 * w + l15;
        h1s[il][j] = fmaxf(acc2[r] + gc1_b[j], 0.f);
    }
    __syncthreads();
    if (t < 160) {
        int row = t / 10, ns = t - row * 10;
        float a2 = 0.f;
#pragma unroll
        for (int j = 0; j < 64; ++j) a2 += h1s[row][j] * gc2_w[j * 10 + ns];
        h1g[(bb * 512 + i0 + row) * 10 + ns] = a2;
    }
}

// ---------------- K4: ospout, 16 rows/block -------------------------------
__global__ __launch_bounds__(256) void ospout_kernel(
    const unsigned short* __restrict__ adjmix, const float* __restrict__ h1g,
    const float* __restrict__ gc2_b, const float* __restrict__ lh,
    const float* __restrict__ out_w, const float* __restrict__ out_b,
    float* __restrict__ out)
{
    int r0 = blockIdx.x * 16;
    int bb = r0 >> 9;
    int wid = threadIdx.x >> 6, lane = threadIdx.x & 63;
    __shared__ float Bsm[10][512];
    __shared__ float ow[8][80];
    __shared__ float ob[8], g2b[10];
    for (int u = threadIdx.x; u < 5120; u += 256) {
        int k = u / 10, ns = u - k * 10;
        Bsm[ns][k] = h1g[bb * 5120 + u];
    }
    if (threadIdx.x < 8)  ob[threadIdx.x]  = out_b[threadIdx.x];
    if (threadIdx.x < 10) g2b[threadIdx.x] = gc2_b[threadIdx.x];
    for (int u = threadIdx.x; u < 592; u += 256) {
        int hh = u / 74, c = u - hh * 74;
        ow[hh][c] = out_w[u];
    }
    __syncthreads();
#pragma unroll
    for (int half = 0; half < 4; ++half) {
        int row = r0 + half * 4 + wid, m = row & 511;
        const unsigned short* Ar = adjmix + row * 512;
        float a[8];
#pragma unroll
        for (int q = 0; q < 8; ++q) a[q] = bf2f(Ar[lane + 64 * q]);
        float os[10];
#pragma unroll
        for (int ns = 0; ns < 10; ++ns) {
            float s = 0.f;
#pragma unroll
            for (int q = 0; q < 8; ++q) s += a[q] * Bsm[ns][lane + 64 * q];
#pragma unroll
            for (int off = 32; off; off >>= 1) s += __shfl_xor(s, off);
            os[ns] = fmaxf(s + g2b[ns], 0.f);
        }
        float lv = lh[row * 64 + lane];
#pragma unroll
        for (int hh = 0; hh < 8; ++hh) {
            float t1 = lv * ow[hh][10 + lane];
#pragma unroll
            for (int off = 32; off; off >>= 1) t1 += __shfl_xor(t1, off);
            if (lane == hh) {
                float acc = ob[hh] + t1;
#pragma unroll
                for (int ns = 0; ns < 10; ++ns) acc += os[ns] * ow[hh][ns];
                out[bb * 4096 + hh * 512 + m] = acc;
            }
        }
    }
}

// ---------------- launch ---------------------------------------------------
extern "C" void kernel_launch(void* const* d_in, const int* in_sizes, int n_in,
                              void* d_out, int out_size, void* d_ws, size_t ws_size,
                              hipStream_t stream)
{
    const float* x       = (const float*)d_in[0];
    const float* adj     = (const float*)d_in[1];
    const float* Wih     = (const float*)d_in[2];
    const float* Whh     = (const float*)d_in[3];
    const float* bih     = (const float*)d_in[4];
    const float* bhh     = (const float*)d_in[5];
    const float* W1      = (const float*)d_in[6];
    const float* W2      = (const float*)d_in[7];
    const float* b1      = (const float*)d_in[8];
    const float* V       = (const float*)d_in[9];
    const float* bv      = (const float*)d_in[10];
    const float* Wb      = (const float*)d_in[11];
    const float* wb      = (const float*)d_in[12];
    const float* conv_w  = (const float*)d_in[13];
    const float* conv_b  = (const float*)d_in[14];
    const float* convl_w = (const float*)d_in[15];
    const float* convl_b = (const float*)d_in[16];
    const float* gc1_w   = (const float*)d_in[17];
    const float* gc1_b   = (const float*)d_in[18];
    const float* gc2_w   = (const float*)d_in[19];
    const float* gc2_b   = (const float*)d_in[20];
    const float* out_w   = (const float*)d_in[21];
    const float* out_b   = (const float*)d_in[22];

    float* ws    = (float*)d_ws;
    float* lh    = ws;                  // 524288
    float* e1    = lh + 524288;         // 262144
    float* e2    = e1 + 262144;         // 262144
    float* nrmss = e2 + 262144;         // 8192
    float* h1g   = nrmss + 8192;        // 81920
    unsigned short* amxb    = (unsigned short*)(h1g + 81920);  // 4194304
    unsigned short* adjmixb = amxb + 4194304;                  // 4194304
    unsigned short* WbT     = adjmixb + 4194304;               // 262144
    unsigned short* rgT     = WbT + 262144;                    // 524288

    fused1_kernel<<<544, 256, 0, stream>>>(
        x, Wih, Whh, bih, bhh, W1, W2, lh, e1, e2,
        conv_w, conv_b, convl_w, convl_b, gc1_w, rgT, Wb, WbT, nrmss);
    amx_kernel<<<dim3(8, 8, 16), 256, 0, stream>>>(e1, e2, b1, V, bv,
                                                   amxb, nrmss);
    gemm_adjmix_h1<<<dim3(32, 16), 256, 0, stream>>>(
        amxb, WbT, wb, adj, nrmss, adjmixb, rgT, gc1_b, gc2_w, h1g);
    ospout_kernel<<<512, 256, 0, stream>>>(adjmixb, h1g, gc2_b, lh,
                                           out_w, out_b, (float*)d_out);
}

// Round 7
// 245.038 us; speedup vs baseline: 1.0867x; 1.0867x over previous
//
#include <hip/hip_runtime.h>

// dims: B=16 W=32 M=512 NH=64 HALF=32 K=8 H=8 LK=16 LOUT=2 NSP=10 GCIN=24
// rows = B*M = 8192. Reference dtypes fp32; bf16 internally for MFMA.
// 4 dispatches: fused1(rnn+e+conv+rg | wbt | zero), amx,
// gemm_adjmix_h1 (merged K3+K4), ospout(+final proj).
// Session calibration: dispatch boundary ~24us (cross-XCD L2 flush);
// baseline K3+K4 ~6us. R5/R6 merge failed because __syncthreads emits
// s_waitcnt vmcnt(0) -> register prefetch drained at every barrier ->
// 64 latency-serial iters (~900cy each). R7: Part A is BARRIER-FREE --
// MFMA fragments loaded directly from global (8 contiguous bf16 = int4),
// rn-scaled in-register, k-outer, acc[4][4] static. 8 outer k-steps of
// exposed latency instead of 64. Part B verbatim from R5 (proven) plus a
// __syncthreads before its prologue (Part A now writes all cols late).

typedef __attribute__((ext_vector_type(8))) short bf16x8;
typedef __attribute__((ext_vector_type(4))) float f32x4;
#define MFMA16 __builtin_amdgcn_mfma_f32_16x16x32_bf16

__device__ __forceinline__ unsigned short f2bf(float f) {
    unsigned u = __float_as_uint(f);
    u += 0x7fff + ((u >> 16) & 1);          // RNE
    return (unsigned short)(u >> 16);
}
__device__ __forceinline__ float bf2f(unsigned short h) {
    return __uint_as_float(((unsigned)h) << 16);
}
__device__ __forceinline__ float fast_tanh(float x) {
    float e = __expf(2.f * x);
    return 1.f - 2.f / (e + 1.f);
}

// ---------------- K1: fused1 ----------------------------------------------
__global__ __launch_bounds__(256) void fused1_kernel(
    const float* __restrict__ x, const float* __restrict__ Wih,
    const float* __restrict__ Whh, const float* __restrict__ bih,
    const float* __restrict__ bhh, const float* __restrict__ W1,
    const float* __restrict__ W2, float* __restrict__ lh,
    float* __restrict__ e1, float* __restrict__ e2,
    const float* __restrict__ conv_w, const float* __restrict__ conv_b,
    const float* __restrict__ convl_w, const float* __restrict__ convl_b,
    const float* __restrict__ gc1_w, unsigned short* __restrict__ rgT,
    const float* __restrict__ Wb, unsigned short* __restrict__ WbT,
    float* __restrict__ nrmss)
{
    __shared__ __align__(16) char smem[12160];
    int blk = blockIdx.x, t = threadIdx.x;

    if (blk < 256) {
        int wid = t >> 6, lane = t & 63;
        int rowblk = blk * 32;
        int b = rowblk >> 9, mb = rowblk & 511;
        float* xs = (float*)smem;                               // [32][32]
        unsigned short* hs = (unsigned short*)(smem + 4096);    // [2][16][72]
        float* rrs = (float*)(smem + 8704);                     // [32][25]

        for (int u = t; u < 1024; u += 256) {
            int tt = u >> 5, c = u & 31;
            xs[tt * 32 + c] = x[(b * 32 + tt) * 512 + mb + c];
        }
        for (int u = t; u < 2304; u += 256) hs[u] = 0;
        __syncthreads();

        if (wid < 2) {
            // RNN (waves 0,1; 16 series each)
            int l15 = lane & 15, quad = lane >> 4;
            int row0 = rowblk + wid * 16;
            unsigned short* hw0 = hs + wid * 1152;

            bf16x8 afr[4][2];
#pragma unroll
            for (int mt = 0; mt < 4; ++mt)
#pragma unroll
                for (int hf = 0; hf < 2; ++hf) {
                    const float* src = Whh + (16 * mt + l15) * 64 + 32 * hf + quad * 8;
                    union { bf16x8 v; unsigned short u[8]; } tmp;
#pragma unroll
                    for (int j = 0; j < 8; ++j) tmp.u[j] = f2bf(src[j]);
                    afr[mt][hf] = tmp.v;
                }
            bf16x8 wfr[2][2][2];
#pragma unroll
            for (int e = 0; e < 2; ++e)
#pragma unroll
                for (int nt = 0; nt < 2; ++nt)
#pragma unroll
                    for (int kf = 0; kf < 2; ++kf) {
                        const float* Wsrc = (e ? W2 : W1);
                        const float* src = Wsrc + (16 * nt + l15) * 64 + 32 * kf + quad * 8;
                        union { bf16x8 v; unsigned short u[8]; } tmp;
#pragma unroll
                        for (int j = 0; j < 8; ++j) tmp.u[j] = f2bf(src[j]);
                        wfr[e][nt][kf] = tmp.v;
                    }
            float wihv[4][4], bsv[4][4];
#pragma unroll
            for (int mt = 0; mt < 4; ++mt)
#pragma unroll
                for (int r = 0; r < 4; ++r) {
                    int n = 16 * mt + quad * 4 + r;
                    wihv[mt][r] = Wih[n];
                    bsv[mt][r]  = bih[n] + bhh[n];
                }

            float th[4][4];
            for (int tstep = 0; tstep < 32; ++tstep) {
                bf16x8 b0 = *(bf16x8*)(hw0 + l15 * 72 + quad * 8);
                bf16x8 b1 = *(bf16x8*)(hw0 + l15 * 72 + 32 + quad * 8);
                float xt = xs[tstep * 32 + wid * 16 + l15];
                f32x4 acc[4];
#pragma unroll
                for (int mt = 0; mt < 4; ++mt) {
                    f32x4 z = {0.f, 0.f, 0.f, 0.f};
                    acc[mt] = MFMA16(afr[mt][0], b0, z, 0, 0, 0);
                    acc[mt] = MFMA16(afr[mt][1], b1, acc[mt], 0, 0, 0);
                }
#pragma unroll
                for (int mt = 0; mt < 4; ++mt) {
                    ushort4 hwv;
#pragma unroll
                    for (int r = 0; r < 4; ++r)
                        th[mt][r] = fast_tanh(acc[mt][r] + xt * wihv[mt][r] + bsv[mt][r]);
                    hwv.x = f2bf(th[mt][0]); hwv.y = f2bf(th[mt][1]);
                    hwv.z = f2bf(th[mt][2]); hwv.w = f2bf(th[mt][3]);
                    *(ushort4*)(hw0 + l15 * 72 + 16 * mt + quad * 4) = hwv;
                }
            }
#pragma unroll
            for (int mt = 0; mt < 4; ++mt)
                *(float4*)(lh + (row0 + l15) * 64 + 16 * mt + quad * 4) =
                    make_float4(th[mt][0], th[mt][1], th[mt][2], th[mt][3]);

            bf16x8 a0 = *(bf16x8*)(hw0 + l15 * 72 + quad * 8);
            bf16x8 a1 = *(bf16x8*)(hw0 + l15 * 72 + 32 + quad * 8);
#pragma unroll
            for (int e = 0; e < 2; ++e) {
                float* dst = e ? e2 : e1;
#pragma unroll
                for (int nt = 0; nt < 2; ++nt) {
                    f32x4 z = {0.f, 0.f, 0.f, 0.f};
                    f32x4 ee = MFMA16(a0, wfr[e][nt][0], z, 0, 0, 0);
                    ee = MFMA16(a1, wfr[e][nt][1], ee, 0, 0, 0);
#pragma unroll
                    for (int r = 0; r < 4; ++r)
                        dst[(row0 + quad * 4 + r) * 32 + 16 * nt + l15] = ee[r];
                }
            }
        } else {
            // conv + rg (waves 2,3; 16 rows each)
            int wid2 = wid - 2;
#pragma unroll
            for (int rep = 0; rep < 2; ++rep) {
                int task = rep * 64 + lane;            // 128 tasks = 16 rows x 8 k
                int rl = wid2 * 16 + (task >> 3);
                int k  = task & 7;
                float s = conv_b[k];
                for (int w = 0; w < 32; ++w) s += xs[w * 32 + rl] * conv_w[k * 32 + w];
                float l0 = convl_b[k], l1 = l0;
                for (int tt = 0; tt < 16; ++tt) {
                    float wv = convl_w[k * 16 + tt];
                    l0 += xs[(2 * tt) * 32 + rl] * wv;
                    l1 += xs[(2 * tt + 1) * 32 + rl] * wv;
                }
                rrs[rl * 25 + k * 3 + 0] = fmaxf(s, 0.f);
                rrs[rl * 25 + k * 3 + 1] = fmaxf(l0, 0.f);
                rrs[rl * 25 + k * 3 + 2] = fmaxf(l1, 0.f);
            }
            // intra-wave LDS RAW: in-order DS per wave; no cross-wave dep
            __builtin_amdgcn_wave_barrier();
            int rl = wid2 * 16 + (lane & 15);
            int nb = lane >> 4;
#pragma unroll
            for (int q = 0; q < 16; ++q) {
                int n = nb * 16 + q;
                float acc = 0.f;
#pragma unroll
                for (int c = 0; c < 24; ++c) acc += rrs[rl * 25 + c] * gc1_w[c * 64 + n];
                rgT[b * 32768 + n * 512 + mb + rl] = f2bf(acc);
            }
        }
    } else if (blk < 512) {
        // ---------------- Wb transpose ----------------
        int bid = blk - 256;
        int nb = (bid & 15) * 32, kb = (bid >> 4) * 32;
        float* tile = (float*)smem;             // [32][33]
        for (int u = t; u < 1024; u += 256) {
            int r = u >> 5, c = u & 31;
            tile[r * 33 + c] = Wb[(kb + r) * 512 + nb + c];
        }
        __syncthreads();
        for (int u = t; u < 1024; u += 256) {
            int r = u >> 5, c = u & 31;
            WbT[(nb + r) * 512 + kb + c] = f2bf(tile[c * 33 + r]);
        }
    } else {
        nrmss[(blk - 512) * 256 + t] = 0.f;
    }
}

// ---------------- K2: a_mx 4x4/thread, factorized exp, fused sumsq --------
__global__ __launch_bounds__(256) void amx_kernel(
    const float* __restrict__ e1, const float* __restrict__ e2,
    const float* __restrict__ b1p, const float* __restrict__ Vp,
    const float* __restrict__ bvp, unsigned short* __restrict__ amxb,
    float* __restrict__ nrmss)
{
    int bb = blockIdx.z;
    int i0 = blockIdx.y * 64, j0 = blockIdx.x * 64;
    __shared__ float e2s[64][33], e1s[64][33];
    __shared__ float Vs[32];
    __shared__ float red[16][68];
    int t = threadIdx.x;
    for (int u = t; u < 2048; u += 256) {
        int r = u >> 5, c = u & 31;
        e2s[r][c] = e2[(bb * 512 + i0 + r) * 32 + c];
        e1s[r][c] = e1[(bb * 512 + j0 + r) * 32 + c] + b1p[c];
    }
    if (t < 32) Vs[t] = Vp[t];
    __syncthreads();
    int ti = (t >> 4) * 4, tj = (t & 15) * 4;
    float acc[4][4] = {};
#pragma unroll
    for (int h = 0; h < 32; ++h) {
        float vv = Vs[h];
        float xi[4], yj[4], Exi[4], Eyj[4];
#pragma unroll
        for (int p = 0; p < 4; ++p) { xi[p] = e2s[ti + p][h]; Exi[p] = __expf(xi[p]); }
#pragma unroll
        for (int q = 0; q < 4; ++q) { yj[q] = e1s[tj + q][h]; Eyj[q] = __expf(yj[q]); }
#pragma unroll
        for (int p = 0; p < 4; ++p)
#pragma unroll
            for (int q = 0; q < 4; ++q) {
                float v = xi[p] + yj[q];
                float prod = Exi[p] * Eyj[q];
                float el = v > 0.f ? v : prod - 1.f;  // exp(xi+yj)=Exi*Eyj
                acc[p][q] += vv * el;
            }
    }
    float bv = bvp[0];
    float ss[4] = {0.f, 0.f, 0.f, 0.f};
#pragma unroll
    for (int p = 0; p < 4; ++p) {
        float v0 = acc[p][0] + bv, v1 = acc[p][1] + bv;
        float v2 = acc[p][2] + bv, v3 = acc[p][3] + bv;
        ushort4 o;
        o.x = f2bf(v0); o.y = f2bf(v1); o.z = f2bf(v2); o.w = f2bf(v3);
        *(ushort4*)(amxb + (bb * 512 + i0 + ti + p) * 512 + j0 + tj) = o;
        ss[0] += v0 * v0; ss[1] += v1 * v1; ss[2] += v2 * v2; ss[3] += v3 * v3;
    }
#pragma unroll
    for (int q = 0; q < 4; ++q) red[t >> 4][tj + q] = ss[q];
    __syncthreads();
    if (t < 64) {
        float s = 0.f;
#pragma unroll
        for (int g = 0; g < 16; ++g) s += red[g][t];
        atomicAdd(&nrmss[bb * 512 + j0 + t], s);
    }
}

// ---------------- K3: gemm_adjmix + gemm_h1 merged ------------------------
// Grid (16,16): block owns rows (bb, i0:i0+32). Part A: BARRIER-FREE
// register-fragment GEMM -- wave w owns rows i0+16*(w&1), cols 256*(w>>1);
// A/B fragments loaded straight from global (8 contiguous bf16 = int4),
// A scaled by rn in-register; k-outer, acc[4][4] (static indices). No
// __syncthreads in the loop -> no vmcnt drain -> loads pipeline. Part B:
// h1 from own just-written adjmix rows (R5-proven body) + h1g epilogue.
__global__ __launch_bounds__(256) void gemm_adjmix_h1(
    const unsigned short* __restrict__ amxb, const unsigned short* __restrict__ WbT,
    const float* __restrict__ wbp, const float* __restrict__ adj,
    const float* __restrict__ nrmss, unsigned short* __restrict__ adjmixb,
    const unsigned short* __restrict__ rgT, const float* __restrict__ gc1_b,
    const float* __restrict__ gc2_w, float* __restrict__ h1g)
{
    const int bb = blockIdx.y;
    const int i0 = blockIdx.x * 32;
    __shared__ __align__(16) char smem[25088];
    float* rn = (float*)smem;                            // [512]   -> 2048
    short* As = (short*)(smem + 2048);                   // [32][72] -> 6656
    short* Bs = (short*)(smem + 6656);                   // [64][72] -> 15872
    float (*h1s)[72] = (float (*)[72])(smem + 15872);    // [32][72] -> 25088

    const int t = threadIdx.x, w = t >> 6, lane = t & 63;
    const int l15 = lane & 15, quad = lane >> 4;

    for (int u = t; u < 512; u += 256)
        rn[u] = 1.f / fmaxf(sqrtf(nrmss[bb * 512 + u]), 1e-12f);
    __syncthreads();

    const unsigned short* Ag = amxb + bb * 262144;
    const float wb = wbp[0];
    const int rowb = i0 + 16 * (w & 1);        // wave's 16 output rows
    const int colb = 256 * (w >> 1);           // wave's 256 output cols

    // ---- Part A: 16x256 per wave, k-outer, no barriers -------------------
    f32x4 acc[4][4] = {};                      // [j64][nt]
    const unsigned short* Arow = Ag + (rowb + l15) * 512;
    for (int k0 = 0; k0 < 512; k0 += 64) {
        bf16x8 a0, a1;
        {
            union { int4 v; unsigned short us[8]; } r0, r1;
            r0.v = *(const int4*)(Arow + k0 + quad * 8);
            r1.v = *(const int4*)(Arow + k0 + 32 + quad * 8);
            union { bf16x8 v; unsigned short us[8]; } o0, o1;
            const float* rn0 = rn + k0 + quad * 8;
#pragma unroll
            for (int c = 0; c < 8; ++c) {
                o0.us[c] = f2bf(bf2f(r0.us[c]) * rn0[c]);
                o1.us[c] = f2bf(bf2f(r1.us[c]) * rn0[32 + c]);
            }
            a0 = o0.v; a1 = o1.v;
        }
#pragma unroll
        for (int j64 = 0; j64 < 4; ++j64)
#pragma unroll
        for (int nt = 0; nt < 4; ++nt) {
            const unsigned short* Brow =
                WbT + (colb + j64 * 64 + nt * 16 + l15) * 512 + k0;
            bf16x8 b0 = *(const bf16x8*)(Brow + quad * 8);
            bf16x8 b1 = *(const bf16x8*)(Brow + 32 + quad * 8);
            acc[j64][nt] = MFMA16(a0, b0, acc[j64][nt], 0, 0, 0);
            acc[j64][nt] = MFMA16(a1, b1, acc[j64][nt], 0, 0, 0);
        }
    }
    // Epilogue: sigmoid-gated mix, write adjmix (am matches baseline's
    // bf16 round-trip: f2bf(bf2f(raw)*rn) then bf2f).
#pragma unroll
    for (int j64 = 0; j64 < 4; ++j64)
#pragma unroll
    for (int nt = 0; nt < 4; ++nt)
#pragma unroll
    for (int r = 0; r < 4; ++r) {
        int i = rowb + quad * 4 + r;
        int j = colb + j64 * 64 + nt * 16 + l15;
        float s  = acc[j64][nt][r] + wb;
        float cv = 1.f / (1.f + __expf(-s));
        float am = bf2f(f2bf(bf2f(Ag[i * 512 + j]) * rn[j]));
        float ad = adj[i * 512 + j];
        adjmixb[(bb * 512 + i) * 512 + j] = f2bf(ad * cv + am * (1.f - cv));
    }
    __syncthreads();   // all waves' adjmix stores complete before Part B reads

    // ---- Part B: h1 from own adjmix rows + h1g (R5-proven body) ----------
    const unsigned short* Ag2 = adjmixb + bb * 262144;
    const unsigned short* Bg2 = rgT + bb * 32768;
    const int rt = w & 1, ntb = (w >> 1) * 2;
    const int si = t >> 3, so = t & 7;
    f32x4 acc2[2] = {};
    int4 qa, qb0, qb1;
    {
        qa  = *(const int4*)(Ag2 + (i0 + si) * 512 + so * 8);
        qb0 = *(const int4*)(Bg2 + si * 512 + so * 8);
        qb1 = *(const int4*)(Bg2 + (32 + si) * 512 + so * 8);
    }
    for (int kt = 0; kt < 8; ++kt) {
        __syncthreads();
        *(int4*)(As + si * 72 + so * 8) = qa;
        *(int4*)(Bs + si * 72 + so * 8) = qb0;
        *(int4*)(Bs + (32 + si) * 72 + so * 8) = qb1;
        if (kt < 7) {
            const int k0n = (kt + 1) * 64;
            qa  = *(const int4*)(Ag2 + (i0 + si) * 512 + k0n + so * 8);
            qb0 = *(const int4*)(Bg2 + si * 512 + k0n + so * 8);
            qb1 = *(const int4*)(Bg2 + (32 + si) * 512 + k0n + so * 8);
        }
        __syncthreads();
        bf16x8 a0 = *(bf16x8*)(As + (16 * rt + l15) * 72 + quad * 8);
        bf16x8 a1 = *(bf16x8*)(As + (16 * rt + l15) * 72 + 32 + quad * 8);
#pragma unroll
        for (int q = 0; q < 2; ++q) {
            int nt = ntb + q;
            bf16x8 b0 = *(bf16x8*)(Bs + (16 * nt + l15) * 72 + quad * 8);
            bf16x8 b1 = *(bf16x8*)(Bs + (16 * nt + l15) * 72 + 32 + quad * 8);
            acc2[q] = MFMA16(a0, b0, acc2[q], 0, 0, 0);
            acc2[q] = MFMA16(a1, b1, acc2[q], 0, 0, 0);
        }
    }
#pragma unroll
    for (int q = 0; q < 2; ++q)
#pragma unroll
    for (int r = 0; r < 4; ++r) {
        int il = 16 * rt + quad * 4 + r;
        int j = 16 * (ntb + q) + l15;
        h1s[il][j] = fmaxf(acc2[q][r] + gc1_b[j], 0.f);
    }
    __syncthreads();
    for (int u = t; u < 320; u += 256) {
        int row = u / 10, ns = u - row * 10;
        float a2 = 0.f;
#pragma unroll
        for (int j = 0; j < 64; ++j) a2 += h1s[row][j] * gc2_w[j * 10 + ns];
        h1g[(bb * 512 + i0 + row) * 10 + ns] = a2;
    }
}

// ---------------- K4: ospout, 16 rows/block -------------------------------
__global__ __launch_bounds__(256) void ospout_kernel(
    const unsigned short* __restrict__ adjmix, const float* __restrict__ h1g,
    const float* __restrict__ gc2_b, const float* __restrict__ lh,
    const float* __restrict__ out_w, const float* __restrict__ out_b,
    float* __restrict__ out)
{
    int r0 = blockIdx.x * 16;
    int bb = r0 >> 9;
    int wid = threadIdx.x >> 6, lane = threadIdx.x & 63;
    __shared__ float Bsm[10][512];
    __shared__ float ow[8][80];
    __shared__ float ob[8], g2b[10];
    for (int u = threadIdx.x; u < 5120; u += 256) {
        int k = u / 10, ns = u - k * 10;
        Bsm[ns][k] = h1g[bb * 5120 + u];
    }
    if (threadIdx.x < 8)  ob[threadIdx.x]  = out_b[threadIdx.x];
    if (threadIdx.x < 10) g2b[threadIdx.x] = gc2_b[threadIdx.x];
    for (int u = threadIdx.x; u < 592; u += 256) {
        int hh = u / 74, c = u - hh * 74;
        ow[hh][c] = out_w[u];
    }
    __syncthreads();
#pragma unroll
    for (int half = 0; half < 4; ++half) {
        int row = r0 + half * 4 + wid, m = row & 511;
        const unsigned short* Ar = adjmix + row * 512;
        float a[8];
#pragma unroll
        for (int q = 0; q < 8; ++q) a[q] = bf2f(Ar[lane + 64 * q]);
        float os[10];
#pragma unroll
        for (int ns = 0; ns < 10; ++ns) {
            float s = 0.f;
#pragma unroll
            for (int q = 0; q < 8; ++q) s += a[q] * Bsm[ns][lane + 64 * q];
#pragma unroll
            for (int off = 32; off; off >>= 1) s += __shfl_xor(s, off);
            os[ns] = fmaxf(s + g2b[ns], 0.f);
        }
        float lv = lh[row * 64 + lane];
#pragma unroll
        for (int hh = 0; hh < 8; ++hh) {
            float t1 = lv * ow[hh][10 + lane];
#pragma unroll
            for (int off = 32; off; off >>= 1) t1 += __shfl_xor(t1, off);
            if (lane == hh) {
                float acc = ob[hh] + t1;
#pragma unroll
                for (int ns = 0; ns < 10; ++ns) acc += os[ns] * ow[hh][ns];
                out[bb * 4096 + hh * 512 + m] = acc;
            }
        }
    }
}

// ---------------- launch ---------------------------------------------------
extern "C" void kernel_launch(void* const* d_in, const int* in_sizes, int n_in,
                              void* d_out, int out_size, void* d_ws, size_t ws_size,
                              hipStream_t stream)
{
    const float* x       = (const float*)d_in[0];
    const float* adj     = (const float*)d_in[1];
    const float* Wih     = (const float*)d_in[2];
    const float* Whh     = (const float*)d_in[3];
    const float* bih     = (const float*)d_in[4];
    const float* bhh     = (const float*)d_in[5];
    const float* W1      = (const float*)d_in[6];
    const float* W2      = (const float*)d_in[7];
    const float* b1      = (const float*)d_in[8];
    const float* V       = (const float*)d_in[9];
    const float* bv      = (const float*)d_in[10];
    const float* Wb      = (const float*)d_in[11];
    const float* wb      = (const float*)d_in[12];
    const float* conv_w  = (const float*)d_in[13];
    const float* conv_b  = (const float*)d_in[14];
    const float* convl_w = (const float*)d_in[15];
    const float* convl_b = (const float*)d_in[16];
    const float* gc1_w   = (const float*)d_in[17];
    const float* gc1_b   = (const float*)d_in[18];
    const float* gc2_w   = (const float*)d_in[19];
    const float* gc2_b   = (const float*)d_in[20];
    const float* out_w   = (const float*)d_in[21];
    const float* out_b   = (const float*)d_in[22];

    float* ws    = (float*)d_ws;
    float* lh    = ws;                  // 524288
    float* e1    = lh + 524288;         // 262144
    float* e2    = e1 + 262144;         // 262144
    float* nrmss = e2 + 262144;         // 8192
    float* h1g   = nrmss + 8192;        // 81920
    unsigned short* amxb    = (unsigned short*)(h1g + 81920);  // 4194304
    unsigned short* adjmixb = amxb + 4194304;                  // 4194304
    unsigned short* WbT     = adjmixb + 4194304;               // 262144
    unsigned short* rgT     = WbT + 262144;                    // 524288

    fused1_kernel<<<544, 256, 0, stream>>>(
        x, Wih, Whh, bih, bhh, W1, W2, lh, e1, e2,
        conv_w, conv_b, convl_w, convl_b, gc1_w, rgT, Wb, WbT, nrmss);
    amx_kernel<<<dim3(8, 8, 16), 256, 0, stream>>>(e1, e2, b1, V, bv,
                                                   amxb, nrmss);
    gemm_adjmix_h1<<<dim3(16, 16), 256, 0, stream>>>(
        amxb, WbT, wb, adj, nrmss, adjmixb, rgT, gc1_b, gc2_w, h1g);
    ospout_kernel<<<512, 256, 0, stream>>>(adjmixb, h1g, gc2_b, lh,
                                           out_w, out_b, (float*)d_out);
}

// Round 8
// 214.391 us; speedup vs baseline: 1.2420x; 1.1429x over previous
//
#include <hip/hip_runtime.h>

// dims: B=16 W=32 M=512 NH=64 HALF=32 K=8 H=8 LK=16 LOUT=2 NSP=10 GCIN=24
// rows = B*M = 8192. Reference dtypes fp32; bf16 internally for MFMA.
// 4 dispatches: fused1(rnn+e+conv+rg | wbt->FRAGMENT-ORDER | zero), amx,
// gemm_adjmix_h1 (merged K3+K4), ospout(+final proj).
// Session model: dispatch boundary ~24us; kernels ~28us total; fill ~46us.
// R7 lesson: barrier-free Part A with per-lane 16B fragment loads from
// row-major WbT = 16 L2 segments/instr -> latency-bound 65us. R8: WbT is
// OURS to lay out -- fused1 stores it in MFMA-fragment order (WbTf), so
// Part A's B-loads are coalesced 1KB bursts feeding MFMA straight from
// global: no LDS, no barriers, no scatter. 16-row panels, 512 blocks =
// 2 blocks/CU for TLP. Part B = R6-proven 16-row body.

typedef __attribute__((ext_vector_type(8))) short bf16x8;
typedef __attribute__((ext_vector_type(4))) float f32x4;
#define MFMA16 __builtin_amdgcn_mfma_f32_16x16x32_bf16

__device__ __forceinline__ unsigned short f2bf(float f) {
    unsigned u = __float_as_uint(f);
    u += 0x7fff + ((u >> 16) & 1);          // RNE
    return (unsigned short)(u >> 16);
}
__device__ __forceinline__ float bf2f(unsigned short h) {
    return __uint_as_float(((unsigned)h) << 16);
}
__device__ __forceinline__ float fast_tanh(float x) {
    float e = __expf(2.f * x);
    return 1.f - 2.f / (e + 1.f);
}

// ---------------- K1: fused1 ----------------------------------------------
// blocks [0,256): RNN+e (waves 0-1) | conv+rg (waves 2-3)
// blocks [256,512): Wb transpose -> bf16 in MFMA-FRAGMENT order (WbTf):
//   value Wb[k][j] lands at frag*512 + lane*8 + (k&7), where
//   frag = ((j>>6)*8 + (k>>6))*8 + ((j>>4)&3)*2 + ((k>>5)&1)
//   lane = ((k>>3)&3)*16 + (j&15)
// blocks [512,544): zero nrmss
__global__ __launch_bounds__(256) void fused1_kernel(
    const float* __restrict__ x, const float* __restrict__ Wih,
    const float* __restrict__ Whh, const float* __restrict__ bih,
    const float* __restrict__ bhh, const float* __restrict__ W1,
    const float* __restrict__ W2, float* __restrict__ lh,
    float* __restrict__ e1, float* __restrict__ e2,
    const float* __restrict__ conv_w, const float* __restrict__ conv_b,
    const float* __restrict__ convl_w, const float* __restrict__ convl_b,
    const float* __restrict__ gc1_w, unsigned short* __restrict__ rgT,
    const float* __restrict__ Wb, unsigned short* __restrict__ WbTf,
    float* __restrict__ nrmss)
{
    __shared__ __align__(16) char smem[12160];
    int blk = blockIdx.x, t = threadIdx.x;

    if (blk < 256) {
        int wid = t >> 6, lane = t & 63;
        int rowblk = blk * 32;
        int b = rowblk >> 9, mb = rowblk & 511;
        float* xs = (float*)smem;                               // [32][32]
        unsigned short* hs = (unsigned short*)(smem + 4096);    // [2][16][72]
        float* rrs = (float*)(smem + 8704);                     // [32][25]

        for (int u = t; u < 1024; u += 256) {
            int tt = u >> 5, c = u & 31;
            xs[tt * 32 + c] = x[(b * 32 + tt) * 512 + mb + c];
        }
        for (int u = t; u < 2304; u += 256) hs[u] = 0;
        __syncthreads();

        if (wid < 2) {
            // RNN (waves 0,1; 16 series each)
            int l15 = lane & 15, quad = lane >> 4;
            int row0 = rowblk + wid * 16;
            unsigned short* hw0 = hs + wid * 1152;

            bf16x8 afr[4][2];
#pragma unroll
            for (int mt = 0; mt < 4; ++mt)
#pragma unroll
                for (int hf = 0; hf < 2; ++hf) {
                    const float* src = Whh + (16 * mt + l15) * 64 + 32 * hf + quad * 8;
                    union { bf16x8 v; unsigned short u[8]; } tmp;
#pragma unroll
                    for (int j = 0; j < 8; ++j) tmp.u[j] = f2bf(src[j]);
                    afr[mt][hf] = tmp.v;
                }
            bf16x8 wfr[2][2][2];
#pragma unroll
            for (int e = 0; e < 2; ++e)
#pragma unroll
                for (int nt = 0; nt < 2; ++nt)
#pragma unroll
                    for (int kf = 0; kf < 2; ++kf) {
                        const float* Wsrc = (e ? W2 : W1);
                        const float* src = Wsrc + (16 * nt + l15) * 64 + 32 * kf + quad * 8;
                        union { bf16x8 v; unsigned short u[8]; } tmp;
#pragma unroll
                        for (int j = 0; j < 8; ++j) tmp.u[j] = f2bf(src[j]);
                        wfr[e][nt][kf] = tmp.v;
                    }
            float wihv[4][4], bsv[4][4];
#pragma unroll
            for (int mt = 0; mt < 4; ++mt)
#pragma unroll
                for (int r = 0; r < 4; ++r) {
                    int n = 16 * mt + quad * 4 + r;
                    wihv[mt][r] = Wih[n];
                    bsv[mt][r]  = bih[n] + bhh[n];
                }

            float th[4][4];
            for (int tstep = 0; tstep < 32; ++tstep) {
                bf16x8 b0 = *(bf16x8*)(hw0 + l15 * 72 + quad * 8);
                bf16x8 b1 = *(bf16x8*)(hw0 + l15 * 72 + 32 + quad * 8);
                float xt = xs[tstep * 32 + wid * 16 + l15];
                f32x4 acc[4];
#pragma unroll
                for (int mt = 0; mt < 4; ++mt) {
                    f32x4 z = {0.f, 0.f, 0.f, 0.f};
                    acc[mt] = MFMA16(afr[mt][0], b0, z, 0, 0, 0);
                    acc[mt] = MFMA16(afr[mt][1], b1, acc[mt], 0, 0, 0);
                }
#pragma unroll
                for (int mt = 0; mt < 4; ++mt) {
                    ushort4 hwv;
#pragma unroll
                    for (int r = 0; r < 4; ++r)
                        th[mt][r] = fast_tanh(acc[mt][r] + xt * wihv[mt][r] + bsv[mt][r]);
                    hwv.x = f2bf(th[mt][0]); hwv.y = f2bf(th[mt][1]);
                    hwv.z = f2bf(th[mt][2]); hwv.w = f2bf(th[mt][3]);
                    *(ushort4*)(hw0 + l15 * 72 + 16 * mt + quad * 4) = hwv;
                }
            }
#pragma unroll
            for (int mt = 0; mt < 4; ++mt)
                *(float4*)(lh + (row0 + l15) * 64 + 16 * mt + quad * 4) =
                    make_float4(th[mt][0], th[mt][1], th[mt][2], th[mt][3]);

            bf16x8 a0 = *(bf16x8*)(hw0 + l15 * 72 + quad * 8);
            bf16x8 a1 = *(bf16x8*)(hw0 + l15 * 72 + 32 + quad * 8);
#pragma unroll
            for (int e = 0; e < 2; ++e) {
                float* dst = e ? e2 : e1;
#pragma unroll
                for (int nt = 0; nt < 2; ++nt) {
                    f32x4 z = {0.f, 0.f, 0.f, 0.f};
                    f32x4 ee = MFMA16(a0, wfr[e][nt][0], z, 0, 0, 0);
                    ee = MFMA16(a1, wfr[e][nt][1], ee, 0, 0, 0);
#pragma unroll
                    for (int r = 0; r < 4; ++r)
                        dst[(row0 + quad * 4 + r) * 32 + 16 * nt + l15] = ee[r];
                }
            }
        } else {
            // conv + rg (waves 2,3; 16 rows each)
            int wid2 = wid - 2;
#pragma unroll
            for (int rep = 0; rep < 2; ++rep) {
                int task = rep * 64 + lane;            // 128 tasks = 16 rows x 8 k
                int rl = wid2 * 16 + (task >> 3);
                int k  = task & 7;
                float s = conv_b[k];
                for (int w = 0; w < 32; ++w) s += xs[w * 32 + rl] * conv_w[k * 32 + w];
                float l0 = convl_b[k], l1 = l0;
                for (int tt = 0; tt < 16; ++tt) {
                    float wv = convl_w[k * 16 + tt];
                    l0 += xs[(2 * tt) * 32 + rl] * wv;
                    l1 += xs[(2 * tt + 1) * 32 + rl] * wv;
                }
                rrs[rl * 25 + k * 3 + 0] = fmaxf(s, 0.f);
                rrs[rl * 25 + k * 3 + 1] = fmaxf(l0, 0.f);
                rrs[rl * 25 + k * 3 + 2] = fmaxf(l1, 0.f);
            }
            // intra-wave LDS RAW: in-order DS per wave; no cross-wave dep
            __builtin_amdgcn_wave_barrier();
            int rl = wid2 * 16 + (lane & 15);
            int nb = lane >> 4;
#pragma unroll
            for (int q = 0; q < 16; ++q) {
                int n = nb * 16 + q;
                float acc = 0.f;
#pragma unroll
                for (int c = 0; c < 24; ++c) acc += rrs[rl * 25 + c] * gc1_w[c * 64 + n];
                rgT[b * 32768 + n * 512 + mb + rl] = f2bf(acc);
            }
        }
    } else if (blk < 512) {
        // ---------------- Wb transpose -> fragment order ----------------
        int bid = blk - 256;
        int nb = (bid & 15) * 32, kb = (bid >> 4) * 32;
        float* tile = (float*)smem;             // [32][33]
        for (int u = t; u < 1024; u += 256) {
            int r = u >> 5, c = u & 31;
            tile[r * 33 + c] = Wb[(kb + r) * 512 + nb + c];
        }
        __syncthreads();
        for (int u = t; u < 1024; u += 256) {
            int r = u >> 5, c = u & 31;
            int j = nb + r, k = kb + c;          // value = Wb[k][j]
            int frag = ((j >> 6) * 8 + (k >> 6)) * 8 + ((j >> 4) & 3) * 2
                     + ((k >> 5) & 1);
            int ln = ((k >> 3) & 3) * 16 + (j & 15);
            WbTf[frag * 512 + ln * 8 + (k & 7)] = f2bf(tile[c * 33 + r]);
        }
    } else {
        nrmss[(blk - 512) * 256 + t] = 0.f;
    }
}

// ---------------- K2: a_mx 4x4/thread, factorized exp, fused sumsq --------
__global__ __launch_bounds__(256) void amx_kernel(
    const float* __restrict__ e1, const float* __restrict__ e2,
    const float* __restrict__ b1p, const float* __restrict__ Vp,
    const float* __restrict__ bvp, unsigned short* __restrict__ amxb,
    float* __restrict__ nrmss)
{
    int bb = blockIdx.z;
    int i0 = blockIdx.y * 64, j0 = blockIdx.x * 64;
    __shared__ float e2s[64][33], e1s[64][33];
    __shared__ float Vs[32];
    __shared__ float red[16][68];
    int t = threadIdx.x;
    for (int u = t; u < 2048; u += 256) {
        int r = u >> 5, c = u & 31;
        e2s[r][c] = e2[(bb * 512 + i0 + r) * 32 + c];
        e1s[r][c] = e1[(bb * 512 + j0 + r) * 32 + c] + b1p[c];
    }
    if (t < 32) Vs[t] = Vp[t];
    __syncthreads();
    int ti = (t >> 4) * 4, tj = (t & 15) * 4;
    float acc[4][4] = {};
#pragma unroll
    for (int h = 0; h < 32; ++h) {
        float vv = Vs[h];
        float xi[4], yj[4], Exi[4], Eyj[4];
#pragma unroll
        for (int p = 0; p < 4; ++p) { xi[p] = e2s[ti + p][h]; Exi[p] = __expf(xi[p]); }
#pragma unroll
        for (int q = 0; q < 4; ++q) { yj[q] = e1s[tj + q][h]; Eyj[q] = __expf(yj[q]); }
#pragma unroll
        for (int p = 0; p < 4; ++p)
#pragma unroll
            for (int q = 0; q < 4; ++q) {
                float v = xi[p] + yj[q];
                float prod = Exi[p] * Eyj[q];
                float el = v > 0.f ? v : prod - 1.f;  // exp(xi+yj)=Exi*Eyj
                acc[p][q] += vv * el;
            }
    }
    float bv = bvp[0];
    float ss[4] = {0.f, 0.f, 0.f, 0.f};
#pragma unroll
    for (int p = 0; p < 4; ++p) {
        float v0 = acc[p][0] + bv, v1 = acc[p][1] + bv;
        float v2 = acc[p][2] + bv, v3 = acc[p][3] + bv;
        ushort4 o;
        o.x = f2bf(v0); o.y = f2bf(v1); o.z = f2bf(v2); o.w = f2bf(v3);
        *(ushort4*)(amxb + (bb * 512 + i0 + ti + p) * 512 + j0 + tj) = o;
        ss[0] += v0 * v0; ss[1] += v1 * v1; ss[2] += v2 * v2; ss[3] += v3 * v3;
    }
#pragma unroll
    for (int q = 0; q < 4; ++q) red[t >> 4][tj + q] = ss[q];
    __syncthreads();
    if (t < 64) {
        float s = 0.f;
#pragma unroll
        for (int g = 0; g < 16; ++g) s += red[g][t];
        atomicAdd(&nrmss[bb * 512 + j0 + t], s);
    }
}

// ---------------- K3: gemm_adjmix + gemm_h1 merged ------------------------
// Grid (32,16): block owns rows (bb, i0:i0+16), 2 blocks/CU. Part A:
// barrier-free -- wave w computes 16 rows x cols [128w,128w+128); B-
// fragments are coalesced 1KB bursts from fragment-ordered WbTf straight
// into MFMA operands; A-fragments from amxb (2 loads/k-step, L1-shared
// across waves), rn-scaled in-register. Part B: h1 from own just-written
// adjmix rows (R6-proven 16-row body) + h1g epilogue.
__global__ __launch_bounds__(256, 2) void gemm_adjmix_h1(
    const unsigned short* __restrict__ amxb, const unsigned short* __restrict__ WbTf,
    const float* __restrict__ wbp, const float* __restrict__ adj,
    const float* __restrict__ nrmss, unsigned short* __restrict__ adjmixb,
    const unsigned short* __restrict__ rgT, const float* __restrict__ gc1_b,
    const float* __restrict__ gc2_w, float* __restrict__ h1g)
{
    const int bb = blockIdx.y;
    const int i0 = blockIdx.x * 16;
    __shared__ __align__(16) char smem[18176];
    float* rn = (float*)smem;                            // [512]   -> 2048
    short* As = (short*)(smem + 2048);                   // [16][72] -> 4352
    short* Bs = (short*)(smem + 4352);                   // [64][72] -> 13568
    float (*h1s)[72] = (float (*)[72])(smem + 13568);    // [16][72] -> 18176

    const int t = threadIdx.x, w = t >> 6, lane = t & 63;
    const int l15 = lane & 15, quad = lane >> 4;

    for (int u = t; u < 512; u += 256)
        rn[u] = 1.f / fmaxf(sqrtf(nrmss[bb * 512 + u]), 1e-12f);
    __syncthreads();

    const unsigned short* Ag = amxb + bb * 262144;
    const float wb = wbp[0];
    const int colb = 128 * w;                  // wave's 128 output cols

    // ---- Part A: 16x128 per wave, k-outer, no barriers -------------------
    f32x4 acc[2][4] = {};                      // [j64][nt]
    const unsigned short* Arow = Ag + (i0 + l15) * 512;
    for (int k0c = 0; k0c < 8; ++k0c) {
        const int k0 = k0c * 64;
        bf16x8 a0, a1;
        {
            union { int4 v; unsigned short us[8]; } r0, r1;
            r0.v = *(const int4*)(Arow + k0 + quad * 8);
            r1.v = *(const int4*)(Arow + k0 + 32 + quad * 8);
            union { bf16x8 v; unsigned short us[8]; } o0, o1;
            const float* rn0 = rn + k0 + quad * 8;
#pragma unroll
            for (int c = 0; c < 8; ++c) {
                o0.us[c] = f2bf(bf2f(r0.us[c]) * rn0[c]);
                o1.us[c] = f2bf(bf2f(r1.us[c]) * rn0[32 + c]);
            }
            a0 = o0.v; a1 = o1.v;
        }
#pragma unroll
        for (int j64 = 0; j64 < 2; ++j64) {
            const int jt = 2 * w + j64;
#pragma unroll
            for (int nt = 0; nt < 4; ++nt) {
                const unsigned short* fr =
                    WbTf + (((jt * 8 + k0c) * 4 + nt) * 2) * 512 + lane * 8;
                bf16x8 b0 = *(const bf16x8*)(fr);          // khalf 0
                bf16x8 b1 = *(const bf16x8*)(fr + 512);    // khalf 1
                acc[j64][nt] = MFMA16(a0, b0, acc[j64][nt], 0, 0, 0);
                acc[j64][nt] = MFMA16(a1, b1, acc[j64][nt], 0, 0, 0);
            }
        }
    }
    // Epilogue: sigmoid-gated mix, write adjmix (am = baseline's bf16
    // round-trip of the rn-scaled amx value).
#pragma unroll
    for (int j64 = 0; j64 < 2; ++j64)
#pragma unroll
    for (int nt = 0; nt < 4; ++nt)
#pragma unroll
    for (int r = 0; r < 4; ++r) {
        int i = i0 + quad * 4 + r;
        int j = colb + j64 * 64 + nt * 16 + l15;
        float s  = acc[j64][nt][r] + wb;
        float cv = 1.f / (1.f + __expf(-s));
        float am = bf2f(f2bf(bf2f(Ag[i * 512 + j]) * rn[j]));
        float ad = adj[i * 512 + j];
        adjmixb[(bb * 512 + i) * 512 + j] = f2bf(ad * cv + am * (1.f - cv));
    }
    __syncthreads();   // all waves' adjmix stores done before Part B reads

    // ---- Part B: h1 from own adjmix rows + h1g (R6-proven body) ----------
    const unsigned short* Ag2 = adjmixb + bb * 262144;
    const unsigned short* Bg2 = rgT + bb * 32768;
    const int si = t >> 3, so = t & 7;
    f32x4 acc2 = {0.f, 0.f, 0.f, 0.f};
    int4 qa, qb0, qb1;
    if (t < 128) qa = *(const int4*)(Ag2 + (i0 + si) * 512 + so * 8);
    qb0 = *(const int4*)(Bg2 + si * 512 + so * 8);
    qb1 = *(const int4*)(Bg2 + (32 + si) * 512 + so * 8);
    for (int kt = 0; kt < 8; ++kt) {
        __syncthreads();
        if (t < 128) *(int4*)(As + si * 72 + so * 8) = qa;
        *(int4*)(Bs + si * 72 + so * 8) = qb0;
        *(int4*)(Bs + (32 + si) * 72 + so * 8) = qb1;
        if (kt < 7) {
            const int k0n = (kt + 1) * 64;
            if (t < 128) qa = *(const int4*)(Ag2 + (i0 + si) * 512 + k0n + so * 8);
            qb0 = *(const int4*)(Bg2 + si * 512 + k0n + so * 8);
            qb1 = *(const int4*)(Bg2 + (32 + si) * 512 + k0n + so * 8);
        }
        __syncthreads();
        bf16x8 a0 = *(bf16x8*)(As + l15 * 72 + quad * 8);
        bf16x8 a1 = *(bf16x8*)(As + l15 * 72 + 32 + quad * 8);
        bf16x8 b0 = *(bf16x8*)(Bs + (16 * w + l15) * 72 + quad * 8);
        bf16x8 b1 = *(bf16x8*)(Bs + (16 * w + l15) * 72 + 32 + quad * 8);
        acc2 = MFMA16(a0, b0, acc2, 0, 0, 0);
        acc2 = MFMA16(a1, b1, acc2, 0, 0, 0);
    }
#pragma unroll
    for (int r = 0; r < 4; ++r) {
        int il = quad * 4 + r;
        int j = 16 * w + l15;
        h1s[il][j] = fmaxf(acc2[r] + gc1_b[j], 0.f);
    }
    __syncthreads();
    if (t < 160) {
        int row = t / 10, ns = t - row * 10;
        float a2 = 0.f;
#pragma unroll
        for (int j = 0; j < 64; ++j) a2 += h1s[row][j] * gc2_w[j * 10 + ns];
        h1g[(bb * 512 + i0 + row) * 10 + ns] = a2;
    }
}

// ---------------- K4: ospout, 16 rows/block -------------------------------
__global__ __launch_bounds__(256) void ospout_kernel(
    const unsigned short* __restrict__ adjmix, const float* __restrict__ h1g,
    const float* __restrict__ gc2_b, const float* __restrict__ lh,
    const float* __restrict__ out_w, const float* __restrict__ out_b,
    float* __restrict__ out)
{
    int r0 = blockIdx.x * 16;
    int bb = r0 >> 9;
    int wid = threadIdx.x >> 6, lane = threadIdx.x & 63;
    __shared__ float Bsm[10][512];
    __shared__ float ow[8][80];
    __shared__ float ob[8], g2b[10];
    for (int u = threadIdx.x; u < 5120; u += 256) {
        int k = u / 10, ns = u - k * 10;
        Bsm[ns][k] = h1g[bb * 5120 + u];
    }
    if (threadIdx.x < 8)  ob[threadIdx.x]  = out_b[threadIdx.x];
    if (threadIdx.x < 10) g2b[threadIdx.x] = gc2_b[threadIdx.x];
    for (int u = threadIdx.x; u < 592; u += 256) {
        int hh = u / 74, c = u - hh * 74;
        ow[hh][c] = out_w[u];
    }
    __syncthreads();
#pragma unroll
    for (int half = 0; half < 4; ++half) {
        int row = r0 + half * 4 + wid, m = row & 511;
        const unsigned short* Ar = adjmix + row * 512;
        float a[8];
#pragma unroll
        for (int q = 0; q < 8; ++q) a[q] = bf2f(Ar[lane + 64 * q]);
        float os[10];
#pragma unroll
        for (int ns = 0; ns < 10; ++ns) {
            float s = 0.f;
#pragma unroll
            for (int q = 0; q < 8; ++q) s += a[q] * Bsm[ns][lane + 64 * q];
#pragma unroll
            for (int off = 32; off; off >>= 1) s += __shfl_xor(s, off);
            os[ns] = fmaxf(s + g2b[ns], 0.f);
        }
        float lv = lh[row * 64 + lane];
#pragma unroll
        for (int hh = 0; hh < 8; ++hh) {
            float t1 = lv * ow[hh][10 + lane];
#pragma unroll
            for (int off = 32; off; off >>= 1) t1 += __shfl_xor(t1, off);
            if (lane == hh) {
                float acc = ob[hh] + t1;
#pragma unroll
                for (int ns = 0; ns < 10; ++ns) acc += os[ns] * ow[hh][ns];
                out[bb * 4096 + hh * 512 + m] = acc;
            }
        }
    }
}

// ---------------- launch ---------------------------------------------------
extern "C" void kernel_launch(void* const* d_in, const int* in_sizes, int n_in,
                              void* d_out, int out_size, void* d_ws, size_t ws_size,
                              hipStream_t stream)
{
    const float* x       = (const float*)d_in[0];
    const float* adj     = (const float*)d_in[1];
    const float* Wih     = (const float*)d_in[2];
    const float* Whh     = (const float*)d_in[3];
    const float* bih     = (const float*)d_in[4];
    const float* bhh     = (const float*)d_in[5];
    const float* W1      = (const float*)d_in[6];
    const float* W2      = (const float*)d_in[7];
    const float* b1      = (const float*)d_in[8];
    const float* V       = (const float*)d_in[9];
    const float* bv      = (const float*)d_in[10];
    const float* Wb      = (const float*)d_in[11];
    const float* wb      = (const float*)d_in[12];
    const float* conv_w  = (const float*)d_in[13];
    const float* conv_b  = (const float*)d_in[14];
    const float* convl_w = (const float*)d_in[15];
    const float* convl_b = (const float*)d_in[16];
    const float* gc1_w   = (const float*)d_in[17];
    const float* gc1_b   = (const float*)d_in[18];
    const float* gc2_w   = (const float*)d_in[19];
    const float* gc2_b   = (const float*)d_in[20];
    const float* out_w   = (const float*)d_in[21];
    const float* out_b   = (const float*)d_in[22];

    float* ws    = (float*)d_ws;
    float* lh    = ws;                  // 524288
    float* e1    = lh + 524288;         // 262144
    float* e2    = e1 + 262144;         // 262144
    float* nrmss = e2 + 262144;         // 8192
    float* h1g   = nrmss + 8192;        // 81920
    unsigned short* amxb    = (unsigned short*)(h1g + 81920);  // 4194304
    unsigned short* adjmixb = amxb + 4194304;                  // 4194304
    unsigned short* WbTf    = adjmixb + 4194304;               // 262144
    unsigned short* rgT     = WbTf + 262144;                   // 524288

    fused1_kernel<<<544, 256, 0, stream>>>(
        x, Wih, Whh, bih, bhh, W1, W2, lh, e1, e2,
        conv_w, conv_b, convl_w, convl_b, gc1_w, rgT, Wb, WbTf, nrmss);
    amx_kernel<<<dim3(8, 8, 16), 256, 0, stream>>>(e1, e2, b1, V, bv,
                                                   amxb, nrmss);
    gemm_adjmix_h1<<<dim3(32, 16), 256, 0, stream>>>(
        amxb, WbTf, wb, adj, nrmss, adjmixb, rgT, gc1_b, gc2_w, h1g);
    ospout_kernel<<<512, 256, 0, stream>>>(adjmixb, h1g, gc2_b, lh,
                                           out_w, out_b, (float*)d_out);
}